// Round 3
// baseline (947.237 us; speedup 1.0000x reference)
//
#include <hip/hip_runtime.h>
#include <stdint.h>

// Problem constants
#define T_  512
#define B_  256
#define F_  512
#define H_  128
#define MH_ 64
#define A_  8
#define OUT0 1179648   // T*B*(A+1)
#define OUT1 32768     // B*H

typedef float f32x4 __attribute__((ext_vector_type(4)));
typedef __bf16 bfrag8 __attribute__((ext_vector_type(8)));
typedef unsigned short u16;
typedef unsigned int u32;

// Workspace layout (bytes)
#define WS_GATES 0u
#define WS_HSEQ  134217728u
#define WS_WIH   167772160u
#define WS_WHH   168296448u
#define WS_WP1   168427520u
#define WS_WV1   168443904u

__device__ inline u16 f2bf(float f) {
  union { float f; u32 u; } v; v.f = f;
  u32 u = v.u;
  u32 r = (u + 0x7FFFu + ((u >> 16) & 1u)) >> 16;
  return (u16)r;
}
__device__ inline float bf2f(u16 b) {
  union { u32 u; float f; } v; v.u = ((u32)b) << 16;
  return v.f;
}

__device__ inline float fexp2(float x) {
#if __has_builtin(__builtin_amdgcn_exp2f)
  return __builtin_amdgcn_exp2f(x);
#else
  return exp2f(x);
#endif
}
__device__ inline float frcp(float x) {
#if __has_builtin(__builtin_amdgcn_rcpf)
  return __builtin_amdgcn_rcpf(x);
#else
  return 1.0f / x;
#endif
}
__device__ inline float sig_(float x) {
  return frcp(1.0f + fexp2(-1.44269504f * x));
}
// NaN-free tanh without clamp: 1 - 2/(exp2(2.885x)+1)
__device__ inline float tanh_(float x) {
  float t = fexp2(2.88539008f * x);
  return 1.0f - 2.0f * frcp(t + 1.0f);
}
// select a[q] from f32x4 with cndmasks (q in 0..3, per-lane, loop-invariant masks)
__device__ inline float sel4(f32x4 a, int q) {
  float s01 = (q & 1) ? a[1] : a[0];
  float s23 = (q & 1) ? a[3] : a[2];
  return (q & 2) ? s23 : s01;
}

__device__ inline f32x4 mfma16(bfrag8 a, bfrag8 b, f32x4 c) {
  return __builtin_amdgcn_mfma_f32_16x16x32_bf16(a, b, c, 0, 0, 0);
}

__device__ inline void gld16(const void* g, void* l) {
  __builtin_amdgcn_global_load_lds((const __attribute__((address_space(1))) void*)g,
                                   (__attribute__((address_space(3))) void*)l, 16, 0, 0);
}

// LDS-only barrier: drain LDS writes, DO NOT drain vmem (no vmcnt(0) stall).
// Cross-wave data exchange in k2 is exclusively through LDS, so this is sufficient.
__device__ inline void lds_barrier() {
  __asm__ __volatile__("s_waitcnt lgkmcnt(0)\n\ts_barrier" ::: "memory");
}

// ---------------- Kernel 0: weight conversion / swizzle ----------------
__global__ __launch_bounds__(256) void k0_prep(const float* __restrict__ W_ih,
                                               const float* __restrict__ W_hh,
                                               const float* __restrict__ W_p1,
                                               const float* __restrict__ W_v1,
                                               u16* __restrict__ wih_swz,
                                               u16* __restrict__ whh_bf,
                                               u16* __restrict__ wp1s,
                                               u16* __restrict__ wv1s) {
  int idx = blockIdx.x * 256 + threadIdx.x;
  if (idx < 262144) {
    int i = idx & 7, L = (idx >> 3) & 63, kb = (idx >> 9) & 15, nt = idx >> 13;
    wih_swz[idx] = f2bf(W_ih[(nt * 16 + (L & 15)) * 512 + kb * 32 + ((L >> 4) << 3) + i]);
  } else if (idx < 262144 + 65536) {
    int j = idx - 262144;
    whh_bf[j] = f2bf(W_hh[j]);
  } else if (idx < 262144 + 65536 + 8192) {
    int j = idx - (262144 + 65536);
    int i = j & 7, L = (j >> 3) & 63, kb = (j >> 9) & 3, nt = j >> 11;
    wp1s[j] = f2bf(W_p1[(kb * 32 + ((L >> 4) << 3) + i) * 64 + nt * 16 + (L & 15)]);
  } else if (idx < 262144 + 65536 + 16384) {
    int j = idx - (262144 + 65536 + 8192);
    int i = j & 7, L = (j >> 3) & 63, kb = (j >> 9) & 3, nt = j >> 11;
    wv1s[j] = f2bf(W_v1[(kb * 32 + ((L >> 4) << 3) + i) * 64 + nt * 16 + (L & 15)]);
  }
}

// ---------------- Kernel 1: gates_pre = x @ W_ih^T + b_ih + b_hh (bf16 out) ----------------
// 128M x 512N per block (1024 blocks): x is read exactly once, full-cacheline coalesced.
// Output in fragment-swizzled layout (see k2 read side):
//   u16 idx = (chunk*2+rp)*128 + (mlrow*16+lcol)*2 + rl
//   chunk = (mblock*8 + mt)*32 + nt'  with nt' = (nt&7)*4 + (nt>>3)   [gate-index-minor]
//   m = mblock*128 + mt*16 + mlrow*4 + rp*2 + rl,  col = nt*16 + lcol
__global__ __launch_bounds__(512) void k1_gates(const float* __restrict__ x,
                                                const u16* __restrict__ wih_swz,
                                                const float* __restrict__ b_ih,
                                                const float* __restrict__ b_hh,
                                                u16* __restrict__ gates) {
  __shared__ __align__(16) u16 Abuf[16 * 64 * 8];  // 16 KB
  __shared__ __align__(16) u16 Bbuf[64 * 64 * 8];  // 64 KB
  const int tid = threadIdx.x;
  const int lane = tid & 63;
  const int w = tid >> 6;
  const int lcol = lane & 15;
  const int m0 = blockIdx.x * 128;
  const int mt0 = (w & 1) * 4, nt0 = (w >> 1) * 8;
  f32x4 acc[4][8] = {};

  for (int k0 = 0; k0 < 512; k0 += 64) {
    // B staging: 64 chunks via async global->LDS, 8 per wave
#pragma unroll
    for (int cc = 0; cc < 8; ++cc) {
      int c = w * 8 + cc;
      int ntg = c >> 1;
      int kbg = (k0 >> 5) + (c & 1);
      gld16(wih_swz + (ntg * 16 + kbg) * 512 + lane * 8, &Bbuf[c * 512]);
    }
    // A staging: 16 consecutive threads read one contiguous 256B row-chunk of x
#pragma unroll
    for (int j = 0; j < 4; ++j) {
      int idx = tid + 512 * j;           // 0..2047
      int row = idx >> 4, pos = idx & 15;
      const float4 v = *(const float4*)&x[(m0 + row) * 512 + k0 + pos * 4];
      int c = (row >> 4) * 2 + (pos >> 3);
      int L = (row & 15) + ((pos & 7) >> 1) * 16;
      int i = (pos & 1) * 4;
      ushort4 pk;
      pk.x = f2bf(v.x); pk.y = f2bf(v.y); pk.z = f2bf(v.z); pk.w = f2bf(v.w);
      *(ushort4*)&Abuf[(c * 64 + L) * 8 + i] = pk;
    }
    __syncthreads();
#pragma unroll
    for (int kk = 0; kk < 2; ++kk) {
      bfrag8 af[4], bfr[8];
#pragma unroll
      for (int im = 0; im < 4; ++im)
        af[im] = *(const bfrag8*)&Abuf[(((mt0 + im) * 2 + kk) * 64 + lane) * 8];
#pragma unroll
      for (int in = 0; in < 8; ++in)
        bfr[in] = *(const bfrag8*)&Bbuf[(((nt0 + in) * 2 + kk) * 64 + lane) * 8];
#pragma unroll
      for (int im = 0; im < 4; ++im)
#pragma unroll
        for (int in = 0; in < 8; ++in)
          acc[im][in] = mfma16(af[im], bfr[in], acc[im][in]);
    }
    __syncthreads();
  }
  // epilogue: bias, pack 2 rows into u32, coalesced dword store
  u32* gd = (u32*)gates;
#pragma unroll
  for (int in = 0; in < 8; ++in) {
    int n = (nt0 + in) * 16 + lcol;
    float bias = b_ih[n] + b_hh[n];
#pragma unroll
    for (int im = 0; im < 4; ++im) {
      int chunk = (blockIdx.x * 8 + mt0 + im) * 32 + in * 4 + (w >> 1);
#pragma unroll
      for (int rp = 0; rp < 2; ++rp) {
        u32 lo = f2bf(acc[im][in][2 * rp] + bias);
        u32 hi = f2bf(acc[im][in][2 * rp + 1] + bias);
        gd[(chunk * 2 + rp) * 64 + lane] = lo | (hi << 16);
      }
    }
  }
}

// ---------------- Kernel 2: sequential masked LSTM ----------------
// 64 blocks x 512 threads; block handles 4 batches. Transposed MFMA
// (gates^T = W_hh @ h^T), 1 unit per lane. LDS-only barrier (no vmem drain),
// gates prefetched 2 steps ahead with zero-VALU addressing (swizzled layout),
// hseq store delayed one step, conflict-free 144-u16 h rows.
__global__ __launch_bounds__(512) void k2_lstm(const float* __restrict__ done,
                                               const float* __restrict__ h0,
                                               const float* __restrict__ c0,
                                               const u16* __restrict__ whh_bf,
                                               const u16* __restrict__ gates,
                                               u16* __restrict__ hseq,
                                               float* __restrict__ dout) {
  __shared__ __align__(16) u16 hbuf[2048];  // two 1024-u16 buffers, row stride 144
  const int tid = threadIdx.x;
  const int lane = tid & 63;
  const int w = tid >> 6;            // 0..7, owns h-cols [16w,16w+16)
  const int lrow = lane >> 4, lcol = lane & 15;
  const int bbase = blockIdx.x * 4;
  const int jb = w * 16;
  const int q = lcol >> 2;           // acc reg index
  const int bt = lcol & 3;           // batch slot
  const int hc = jb + lrow * 4 + q;  // this lane's h-column
  const int brow = bbase + bt;       // global batch index

  // swizzled-gates per-lane offset (u16 elements), t=0, g=0
  const int mt_b = (bbase & 127) >> 4;
  const int mlrow = (bbase >> 2) & 3;
  const int rp = bt >> 1, rl = bt & 1;
  const int chunk0 = ((bbase >> 7) * 8 + mt_b) * 32 + w * 4;
  const int goff = (chunk0 * 2 + rp) * 128 + (mlrow * 16 + lrow * 4 + q) * 2 + rl;
  const int soff = brow * 128 + hc;  // hseq per-t offset
  const int rdc = bt * 144 + lrow * 8;
  const int wrc = bt * 144 + hc;

  // Preload W_hh A-operand fragments, reused 512x
  bfrag8 wf[4][4];
#pragma unroll
  for (int g = 0; g < 4; ++g)
#pragma unroll
    for (int kk = 0; kk < 4; ++kk)
      wf[g][kk] = *(const bfrag8*)&whh_bf[(g * 128 + jb + lcol) * 128 + kk * 32 + lrow * 8];

  // init own unit
  const float m0v = 1.0f - done[brow];
  hbuf[wrc] = f2bf(h0[brow * 128 + hc] * m0v);
  float c = c0[brow * 128 + hc] * m0v;
  float hh = 0.0f;
  u16 hb_prev = 0;

  // prefetch gates(t=0,1) and done(t=1)
  u32 gp[4], gpn[4], gpn2[4];
  {
    const u16* g0 = gates + goff;
#pragma unroll
    for (int g = 0; g < 4; ++g) gp[g] = g0[g * 256];
    const u16* g1 = gates + 131072 + goff;
#pragma unroll
    for (int g = 0; g < 4; ++g) gpn[g] = g1[g * 256];
  }
  float dnx = done[B_ + brow];
  float dn2;

  for (int t = 0; t < T_; ++t) {
    lds_barrier();  // LDS visible; vmem stays in flight

    // delayed hseq store: h(t-1) has a full step to drain
    if (t) hseq[(size_t)(t - 1) * 32768 + soff] = hb_prev;

    // prefetch gates(t+2), done(t+2): zero-VALU addressing (scalar t-part + imm offsets)
    const int tg = (t + 2 < T_) ? t + 2 : T_ - 1;
    const u16* gb = gates + (size_t)tg * 131072 + goff;
#pragma unroll
    for (int g = 0; g < 4; ++g) gpn2[g] = gb[g * 256];
    dn2 = done[tg * B_ + brow];

    // h^T B-operand fragments from LDS
    const u16* hp = hbuf + rdc + ((t & 1) << 10);
    bfrag8 hf[4];
#pragma unroll
    for (int kk = 0; kk < 4; ++kk)
      hf[kk] = *(const bfrag8*)(hp + kk * 32);

    f32x4 acc[4] = {};
#pragma unroll
    for (int kk = 0; kk < 4; ++kk)
#pragma unroll
      for (int g = 0; g < 4; ++g)
        acc[g] = mfma16(wf[g][kk], hf[kk], acc[g]);

    float pi = sel4(acc[0], q) + bf2f((u16)gp[0]);
    float pf = sel4(acc[1], q) + bf2f((u16)gp[1]);
    float pg = sel4(acc[2], q) + bf2f((u16)gp[2]);
    float po = sel4(acc[3], q) + bf2f((u16)gp[3]);
    float iv = sig_(pi), fv = sig_(pf), gv = tanh_(pg), ov = sig_(po);
    float cc = fv * c + iv * gv;
    hh = ov * tanh_(cc);
    // reset mask for next step: done is exactly 0.0 or 1.0 -> cndmask
    bool rs = (dnx != 0.0f) && (t < T_ - 1);
    c = rs ? 0.0f : cc;
    u16 hb = f2bf(hh);
    hbuf[wrc + (((t & 1) ^ 1) << 10)] = rs ? (u16)0 : hb;
    hb_prev = hb;

#pragma unroll
    for (int g = 0; g < 4; ++g) { gp[g] = gpn[g]; gpn[g] = gpn2[g]; }
    dnx = dn2;
  }
  // final hseq row + hT, cT (fp32, unmasked)
  hseq[(size_t)(T_ - 1) * 32768 + soff] = hb_prev;
  dout[OUT0 + soff] = hh;
  dout[OUT0 + OUT1 + soff] = c;
}

// ---------------- Kernel 3: MLP heads ----------------
__global__ __launch_bounds__(256) void k3_heads(const u16* __restrict__ hseq,
                                                const u16* __restrict__ wp1s,
                                                const u16* __restrict__ wv1s,
                                                const float* __restrict__ b_p1,
                                                const float* __restrict__ W_p2,
                                                const float* __restrict__ b_p2,
                                                const float* __restrict__ b_v1,
                                                const float* __restrict__ W_v2,
                                                const float* __restrict__ b_v2,
                                                float* __restrict__ out) {
  __shared__ float midp[4][16][68];
  __shared__ float midv[4][16][68];
  __shared__ float wsm[585];  // W_p2(512) ++ W_v2(64) ++ b_p2(8) ++ b_v2(1)
  const int tid = threadIdx.x;
  const int lane = tid & 63, w = tid >> 6;
  const int lrow = lane >> 4, lcol = lane & 15;
  const int r0 = blockIdx.x * 64;

  for (int e = tid; e < 585; e += 256) {
    float v;
    if (e < 512) v = W_p2[e];
    else if (e < 576) v = W_v2[e - 512];
    else if (e < 584) v = b_p2[e - 576];
    else v = b_v2[0];
    wsm[e] = v;
  }

  const int rowA = r0 + w * 16 + lcol;
  bfrag8 af[4];
#pragma unroll
  for (int kk = 0; kk < 4; ++kk)
    af[kk] = *(const bfrag8*)&hseq[rowA * 128 + kk * 32 + lrow * 8];

#pragma unroll
  for (int nt = 0; nt < 4; ++nt) {
    f32x4 ap = {}, av = {};
#pragma unroll
    for (int kk = 0; kk < 4; ++kk) {
      ap = mfma16(af[kk], *(const bfrag8*)&wp1s[((nt * 4 + kk) * 64 + lane) * 8], ap);
      av = mfma16(af[kk], *(const bfrag8*)&wv1s[((nt * 4 + kk) * 64 + lane) * 8], av);
    }
    float bp = b_p1[nt * 16 + lcol], bv = b_v1[nt * 16 + lcol];
#pragma unroll
    for (int r = 0; r < 4; ++r) {
      midp[w][lrow * 4 + r][nt * 16 + lcol] = tanh_(ap[r] + bp);
      midv[w][lrow * 4 + r][nt * 16 + lcol] = tanh_(av[r] + bv);
    }
  }
  __syncthreads();

  for (int o = tid; o < 576; o += 256) {
    int row = o / 9;
    int a = o - row * 9;
    float s;
    if (a < 8) {
      s = wsm[576 + a];
      const float* mrow = &midp[row >> 4][row & 15][0];
#pragma unroll
      for (int n = 0; n < 64; ++n) s += mrow[n] * wsm[n * 8 + a];
    } else {
      s = wsm[584];
      const float* mrow = &midv[row >> 4][row & 15][0];
#pragma unroll
      for (int n = 0; n < 64; ++n) s += mrow[n] * wsm[512 + n];
    }
    out[(r0 + row) * 9 + a] = s;
  }
}

extern "C" void kernel_launch(void* const* d_in, const int* in_sizes, int n_in,
                              void* d_out, int out_size, void* d_ws, size_t ws_size,
                              hipStream_t stream) {
  const float* x    = (const float*)d_in[0];
  const float* done = (const float*)d_in[1];
  const float* h0   = (const float*)d_in[2];
  const float* c0   = (const float*)d_in[3];
  const float* W_ih = (const float*)d_in[4];
  const float* W_hh = (const float*)d_in[5];
  const float* b_ih = (const float*)d_in[6];
  const float* b_hh = (const float*)d_in[7];
  const float* W_p1 = (const float*)d_in[8];
  const float* b_p1 = (const float*)d_in[9];
  const float* W_p2 = (const float*)d_in[10];
  const float* b_p2 = (const float*)d_in[11];
  const float* W_v1 = (const float*)d_in[12];
  const float* b_v1 = (const float*)d_in[13];
  const float* W_v2 = (const float*)d_in[14];
  const float* b_v2 = (const float*)d_in[15];

  char* ws = (char*)d_ws;
  u16* gates   = (u16*)(ws + WS_GATES);
  u16* hseq    = (u16*)(ws + WS_HSEQ);
  u16* wih_swz = (u16*)(ws + WS_WIH);
  u16* whh_bf  = (u16*)(ws + WS_WHH);
  u16* wp1s    = (u16*)(ws + WS_WP1);
  u16* wv1s    = (u16*)(ws + WS_WV1);
  float* out = (float*)d_out;

  k0_prep<<<dim3(1344), dim3(256), 0, stream>>>(W_ih, W_hh, W_p1, W_v1,
                                                wih_swz, whh_bf, wp1s, wv1s);
  k1_gates<<<dim3(1024), dim3(512), 0, stream>>>(x, wih_swz, b_ih, b_hh, gates);
  k2_lstm<<<dim3(64), dim3(512), 0, stream>>>(done, h0, c0, whh_bf, gates, hseq, out);
  k3_heads<<<dim3(2048), dim3(256), 0, stream>>>(hseq, wp1s, wv1s, b_p1, W_p2, b_p2,
                                                 b_v1, W_v2, b_v2, out);
}

// Round 4
// 864.418 us; speedup vs baseline: 1.0958x; 1.0958x over previous
//
#include <hip/hip_runtime.h>
#include <stdint.h>

// Problem constants
#define T_  512
#define B_  256
#define F_  512
#define H_  128
#define MH_ 64
#define A_  8
#define OUT0 1179648   // T*B*(A+1)
#define OUT1 32768     // B*H

typedef float f32x4 __attribute__((ext_vector_type(4)));
typedef __bf16 bfrag8 __attribute__((ext_vector_type(8)));
typedef unsigned short u16;
typedef unsigned int u32;

// Workspace layout (bytes)
#define WS_GATES 0u
#define WS_HSEQ  134217728u
#define WS_WIH   167772160u
#define WS_WHH   168296448u
#define WS_WP1   168427520u
#define WS_WV1   168443904u

__device__ inline u16 f2bf(float f) {
  __bf16 b = (__bf16)f;            // RNE hardware convert
  union { __bf16 b; u16 u; } v; v.b = b;
  return v.u;
}
__device__ inline float bf2f(u16 b) {
  union { u32 u; float f; } v; v.u = ((u32)b) << 16;
  return v.f;
}

__device__ inline float fexp2(float x) {
#if __has_builtin(__builtin_amdgcn_exp2f)
  return __builtin_amdgcn_exp2f(x);
#else
  return exp2f(x);
#endif
}
__device__ inline float frcp(float x) {
#if __has_builtin(__builtin_amdgcn_rcpf)
  return __builtin_amdgcn_rcpf(x);
#else
  return 1.0f / x;
#endif
}
__device__ inline float sig_(float x) {
  return frcp(1.0f + fexp2(-1.44269504f * x));
}
// NaN-free tanh without clamp: 1 - 2/(exp2(2.885x)+1)
__device__ inline float tanh_(float x) {
  float t = fexp2(2.88539008f * x);
  return 1.0f - 2.0f * frcp(t + 1.0f);
}
// select a[q] from f32x4 with cndmasks (q in 0..3, per-lane, loop-invariant masks)
__device__ inline float sel4(f32x4 a, int q) {
  float s01 = (q & 1) ? a[1] : a[0];
  float s23 = (q & 1) ? a[3] : a[2];
  return (q & 2) ? s23 : s01;
}

__device__ inline f32x4 mfma16(bfrag8 a, bfrag8 b, f32x4 c) {
  return __builtin_amdgcn_mfma_f32_16x16x32_bf16(a, b, c, 0, 0, 0);
}

// LDS-only barrier: drain LDS ops, DO NOT drain vmem (no vmcnt(0) stall).
__device__ inline void lds_barrier() {
  __asm__ __volatile__("s_waitcnt lgkmcnt(0)\n\ts_barrier" ::: "memory");
}

__device__ inline bfrag8 cvt8(float4 a, float4 b) {
  bfrag8 r;
  r[0] = (__bf16)a.x; r[1] = (__bf16)a.y; r[2] = (__bf16)a.z; r[3] = (__bf16)a.w;
  r[4] = (__bf16)b.x; r[5] = (__bf16)b.y; r[6] = (__bf16)b.z; r[7] = (__bf16)b.w;
  return r;
}

// ---------------- Kernel 0: weight conversion / swizzle ----------------
__global__ __launch_bounds__(256) void k0_prep(const float* __restrict__ W_ih,
                                               const float* __restrict__ W_hh,
                                               const float* __restrict__ W_p1,
                                               const float* __restrict__ W_v1,
                                               u16* __restrict__ wih_swz,
                                               u16* __restrict__ whh_bf,
                                               u16* __restrict__ wp1s,
                                               u16* __restrict__ wv1s) {
  int idx = blockIdx.x * 256 + threadIdx.x;
  if (idx < 262144) {
    int i = idx & 7, L = (idx >> 3) & 63, kb = (idx >> 9) & 15, nt = idx >> 13;
    wih_swz[idx] = f2bf(W_ih[(nt * 16 + (L & 15)) * 512 + kb * 32 + ((L >> 4) << 3) + i]);
  } else if (idx < 262144 + 65536) {
    int j = idx - 262144;
    whh_bf[j] = f2bf(W_hh[j]);
  } else if (idx < 262144 + 65536 + 8192) {
    int j = idx - (262144 + 65536);
    int i = j & 7, L = (j >> 3) & 63, kb = (j >> 9) & 3, nt = j >> 11;
    wp1s[j] = f2bf(W_p1[(kb * 32 + ((L >> 4) << 3) + i) * 64 + nt * 16 + (L & 15)]);
  } else if (idx < 262144 + 65536 + 16384) {
    int j = idx - (262144 + 65536 + 8192);
    int i = j & 7, L = (j >> 3) & 63, kb = (j >> 9) & 3, nt = j >> 11;
    wv1s[j] = f2bf(W_v1[(kb * 32 + ((L >> 4) << 3) + i) * 64 + nt * 16 + (L & 15)]);
  }
}

// ---------------- Kernel 1: gates_pre = x @ W_ih^T + b_ih + b_hh (bf16 out) ----------------
// LDS-free, barrier-free. 128M x 512N per block (1024 blocks).
// B-fragments are per-wave-exclusive -> loaded straight from pre-swizzled
// wih_swz chunks (1KB coalesced per wave-load, L2-resident 512KB).
// A-fragments loaded straight from fp32 x (2 x float4 per lane) + HW bf16 cvt.
__global__ __launch_bounds__(512, 2) void k1_gates(const float* __restrict__ x,
                                                   const u16* __restrict__ wih_swz,
                                                   const float* __restrict__ b_ih,
                                                   const float* __restrict__ b_hh,
                                                   u16* __restrict__ gates) {
  const int tid = threadIdx.x;
  const int lane = tid & 63;
  const int w = tid >> 6;
  const int lrow = lane >> 4, lcol = lane & 15;
  const int m0 = blockIdx.x * 128;
  const int mt0 = (w & 1) * 4, nt0 = (w >> 1) * 8;
  f32x4 acc[4][8] = {};

  // invariant per-lane bases (zero VALU addressing in the loop: imm/scalar offsets)
  const float* xim[4];
#pragma unroll
  for (int im = 0; im < 4; ++im)
    xim[im] = x + (m0 + (mt0 + im) * 16 + lcol) * 512 + lrow * 8;
  const u16* wbin[8];
#pragma unroll
  for (int in = 0; in < 8; ++in)
    wbin[in] = wih_swz + (nt0 + in) * 8192 + lane * 8;

  for (int kit = 0; kit < 8; ++kit) {
#pragma unroll
    for (int kk = 0; kk < 2; ++kk) {
      const int cofs = kit * 64 + kk * 32;     // fp32 col offset (imm-able)
      const int wofs = (kit * 2 + kk) * 512;   // chunk offset in u16
      bfrag8 bf[8];
#pragma unroll
      for (int in = 0; in < 8; ++in)
        bf[in] = *(const bfrag8*)(wbin[in] + wofs);
      bfrag8 af[4];
#pragma unroll
      for (int im = 0; im < 4; ++im) {
        float4 v0 = *(const float4*)(xim[im] + cofs);
        float4 v1 = *(const float4*)(xim[im] + cofs + 4);
        af[im] = cvt8(v0, v1);
      }
#pragma unroll
      for (int im = 0; im < 4; ++im)
#pragma unroll
        for (int in = 0; in < 8; ++in)
          acc[im][in] = mfma16(af[im], bf[in], acc[im][in]);
    }
  }
  // epilogue: add bias, store bf16 (row-major [m][col])
#pragma unroll
  for (int in = 0; in < 8; ++in) {
    int n = (nt0 + in) * 16 + lcol;
    float bias = b_ih[n] + b_hh[n];
#pragma unroll
    for (int im = 0; im < 4; ++im) {
      int mbase = m0 + (mt0 + im) * 16 + lrow * 4;
#pragma unroll
      for (int r = 0; r < 4; ++r)
        gates[(mbase + r) * 512 + n] = f2bf(acc[im][in][r] + bias);
    }
  }
}

// ---------------- Kernel 2: sequential masked LSTM ----------------
// 64 blocks x 512 threads; block handles 4 batches. Transposed MFMA
// (gates^T = W_hh @ h^T), 1 unit/lane. LDS-only barrier, unroll x4 with 4
// independent gates-register sets (reload-after-use, 3-step lead, no moves),
// conflict-free 144-u16 h rows, row-major gates (block-local cache lines).
__global__ __launch_bounds__(512) void k2_lstm(const float* __restrict__ done,
                                               const float* __restrict__ h0,
                                               const float* __restrict__ c0,
                                               const u16* __restrict__ whh_bf,
                                               const u16* __restrict__ gates,
                                               u16* __restrict__ hseq,
                                               float* __restrict__ dout) {
  __shared__ __align__(16) u16 hbuf[2048];  // two 1024-u16 buffers, row stride 144
  const int tid = threadIdx.x;
  const int lane = tid & 63;
  const int w = tid >> 6;            // 0..7, owns h-cols [16w,16w+16)
  const int lrow = lane >> 4, lcol = lane & 15;
  const int bbase = blockIdx.x * 4;
  const int jb = w * 16;
  const int q = lcol >> 2;           // acc reg index
  const int bt = lcol & 3;           // batch slot
  const int hc = jb + lrow * 4 + q;  // this lane's h-column
  const int brow = bbase + bt;       // global batch index

  const int goff = brow * 512 + hc;  // u16 offset into gates row t
  const int soff = brow * 128 + hc;  // hseq per-t offset
  const int rdc = bt * 144 + lrow * 8;
  const int wrc = bt * 144 + hc;

  // Preload W_hh A-operand fragments, reused 512x
  bfrag8 wf[4][4];
#pragma unroll
  for (int g = 0; g < 4; ++g)
#pragma unroll
    for (int kk = 0; kk < 4; ++kk)
      wf[g][kk] = *(const bfrag8*)&whh_bf[(g * 128 + jb + lcol) * 128 + kk * 32 + lrow * 8];

  // init own unit (buffer 0)
  const float m0v = 1.0f - done[brow];
  hbuf[wrc] = f2bf(h0[brow * 128 + hc] * m0v);
  float c = c0[brow * 128 + hc] * m0v;
  float hh = 0.0f;

  // 4 independent prefetch sets: gp_i = gates(t=i), dn_i = done[i+1]
  u32 gp0[4], gp1[4], gp2[4], gp3[4];
#pragma unroll
  for (int g = 0; g < 4; ++g) {
    gp0[g] = gates[goff + g * 128];
    gp1[g] = gates[131072 + goff + g * 128];
    gp2[g] = gates[262144 + goff + g * 128];
    gp3[g] = gates[393216 + goff + g * 128];
  }
  float dn0 = done[256 + brow];
  float dn1 = done[512 + brow];
  float dn2 = done[768 + brow];
  float dn3 = done[1024 + brow];

#define K2_STEP(GP, DN, RB, WB, T, GUARD) do {                                  \
    lds_barrier();                                                              \
    const u16* hp = hbuf + rdc + (RB)*1024;                                     \
    bfrag8 hf0 = *(const bfrag8*)(hp);                                          \
    bfrag8 hf1 = *(const bfrag8*)(hp + 32);                                     \
    bfrag8 hf2 = *(const bfrag8*)(hp + 64);                                     \
    bfrag8 hf3 = *(const bfrag8*)(hp + 96);                                     \
    f32x4 a0 = {}, a1 = {}, a2 = {}, a3 = {};                                   \
    a0 = mfma16(wf[0][0], hf0, a0); a1 = mfma16(wf[1][0], hf0, a1);             \
    a2 = mfma16(wf[2][0], hf0, a2); a3 = mfma16(wf[3][0], hf0, a3);             \
    a0 = mfma16(wf[0][1], hf1, a0); a1 = mfma16(wf[1][1], hf1, a1);             \
    a2 = mfma16(wf[2][1], hf1, a2); a3 = mfma16(wf[3][1], hf1, a3);             \
    a0 = mfma16(wf[0][2], hf2, a0); a1 = mfma16(wf[1][2], hf2, a1);             \
    a2 = mfma16(wf[2][2], hf2, a2); a3 = mfma16(wf[3][2], hf2, a3);             \
    a0 = mfma16(wf[0][3], hf3, a0); a1 = mfma16(wf[1][3], hf3, a1);             \
    a2 = mfma16(wf[2][3], hf3, a2); a3 = mfma16(wf[3][3], hf3, a3);             \
    float pi = sel4(a0, q) + bf2f((u16)GP[0]);                                  \
    float pf = sel4(a1, q) + bf2f((u16)GP[1]);                                  \
    float pg = sel4(a2, q) + bf2f((u16)GP[2]);                                  \
    float po = sel4(a3, q) + bf2f((u16)GP[3]);                                  \
    { int tg = (T) + 4; if (tg > 511) tg = 511;                                 \
      const u16* gb = gates + (size_t)tg * 131072 + goff;                       \
      GP[0] = gb[0]; GP[1] = gb[128]; GP[2] = gb[256]; GP[3] = gb[384]; }       \
    bool rs = (DN != 0.0f) && (GUARD);                                          \
    { int td = (T) + 5; if (td > 511) td = 511; DN = done[td * 256 + brow]; }   \
    float iv = sig_(pi), fv = sig_(pf), gv = tanh_(pg), ov = sig_(po);          \
    float cc = fv * c + iv * gv;                                                \
    hh = ov * tanh_(cc);                                                        \
    c = rs ? 0.0f : cc;                                                         \
    u16 hb = f2bf(hh);                                                          \
    hseq[(size_t)(T) * 32768 + soff] = hb;                                      \
    hbuf[wrc + (WB)*1024] = rs ? (u16)0 : hb;                                   \
  } while (0)

  for (int tt = 0; tt < T_; tt += 4) {
    K2_STEP(gp0, dn0, 0, 1, tt,     true);
    K2_STEP(gp1, dn1, 1, 0, tt + 1, true);
    K2_STEP(gp2, dn2, 0, 1, tt + 2, true);
    K2_STEP(gp3, dn3, 1, 0, tt + 3, (tt < 508));
  }
#undef K2_STEP

  // hT, cT (fp32, unmasked)
  dout[OUT0 + soff] = hh;
  dout[OUT0 + OUT1 + soff] = c;
}

// ---------------- Kernel 3: MLP heads ----------------
__global__ __launch_bounds__(256) void k3_heads(const u16* __restrict__ hseq,
                                                const u16* __restrict__ wp1s,
                                                const u16* __restrict__ wv1s,
                                                const float* __restrict__ b_p1,
                                                const float* __restrict__ W_p2,
                                                const float* __restrict__ b_p2,
                                                const float* __restrict__ b_v1,
                                                const float* __restrict__ W_v2,
                                                const float* __restrict__ b_v2,
                                                float* __restrict__ out) {
  __shared__ float midp[4][16][68];
  __shared__ float midv[4][16][68];
  __shared__ float wsm[585];  // W_p2(512) ++ W_v2(64) ++ b_p2(8) ++ b_v2(1)
  const int tid = threadIdx.x;
  const int lane = tid & 63, w = tid >> 6;
  const int lrow = lane >> 4, lcol = lane & 15;
  const int r0 = blockIdx.x * 64;

  for (int e = tid; e < 585; e += 256) {
    float v;
    if (e < 512) v = W_p2[e];
    else if (e < 576) v = W_v2[e - 512];
    else if (e < 584) v = b_p2[e - 576];
    else v = b_v2[0];
    wsm[e] = v;
  }

  const int rowA = r0 + w * 16 + lcol;
  bfrag8 af[4];
#pragma unroll
  for (int kk = 0; kk < 4; ++kk)
    af[kk] = *(const bfrag8*)&hseq[rowA * 128 + kk * 32 + lrow * 8];

#pragma unroll
  for (int nt = 0; nt < 4; ++nt) {
    f32x4 ap = {}, av = {};
#pragma unroll
    for (int kk = 0; kk < 4; ++kk) {
      ap = mfma16(af[kk], *(const bfrag8*)&wp1s[((nt * 4 + kk) * 64 + lane) * 8], ap);
      av = mfma16(af[kk], *(const bfrag8*)&wv1s[((nt * 4 + kk) * 64 + lane) * 8], av);
    }
    float bp = b_p1[nt * 16 + lcol], bv = b_v1[nt * 16 + lcol];
#pragma unroll
    for (int r = 0; r < 4; ++r) {
      midp[w][lrow * 4 + r][nt * 16 + lcol] = tanh_(ap[r] + bp);
      midv[w][lrow * 4 + r][nt * 16 + lcol] = tanh_(av[r] + bv);
    }
  }
  __syncthreads();

  for (int o = tid; o < 576; o += 256) {
    int row = o / 9;
    int a = o - row * 9;
    float s;
    if (a < 8) {
      s = wsm[576 + a];
      const float* mrow = &midp[row >> 4][row & 15][0];
#pragma unroll
      for (int n = 0; n < 64; ++n) s += mrow[n] * wsm[n * 8 + a];
    } else {
      s = wsm[584];
      const float* mrow = &midv[row >> 4][row & 15][0];
#pragma unroll
      for (int n = 0; n < 64; ++n) s += mrow[n] * wsm[512 + n];
    }
    out[(r0 + row) * 9 + a] = s;
  }
}

extern "C" void kernel_launch(void* const* d_in, const int* in_sizes, int n_in,
                              void* d_out, int out_size, void* d_ws, size_t ws_size,
                              hipStream_t stream) {
  const float* x    = (const float*)d_in[0];
  const float* done = (const float*)d_in[1];
  const float* h0   = (const float*)d_in[2];
  const float* c0   = (const float*)d_in[3];
  const float* W_ih = (const float*)d_in[4];
  const float* W_hh = (const float*)d_in[5];
  const float* b_ih = (const float*)d_in[6];
  const float* b_hh = (const float*)d_in[7];
  const float* W_p1 = (const float*)d_in[8];
  const float* b_p1 = (const float*)d_in[9];
  const float* W_p2 = (const float*)d_in[10];
  const float* b_p2 = (const float*)d_in[11];
  const float* W_v1 = (const float*)d_in[12];
  const float* b_v1 = (const float*)d_in[13];
  const float* W_v2 = (const float*)d_in[14];
  const float* b_v2 = (const float*)d_in[15];

  char* ws = (char*)d_ws;
  u16* gates   = (u16*)(ws + WS_GATES);
  u16* hseq    = (u16*)(ws + WS_HSEQ);
  u16* wih_swz = (u16*)(ws + WS_WIH);
  u16* whh_bf  = (u16*)(ws + WS_WHH);
  u16* wp1s    = (u16*)(ws + WS_WP1);
  u16* wv1s    = (u16*)(ws + WS_WV1);
  float* out = (float*)d_out;

  k0_prep<<<dim3(1344), dim3(256), 0, stream>>>(W_ih, W_hh, W_p1, W_v1,
                                                wih_swz, whh_bf, wp1s, wv1s);
  k1_gates<<<dim3(1024), dim3(512), 0, stream>>>(x, wih_swz, b_ih, b_hh, gates);
  k2_lstm<<<dim3(64), dim3(512), 0, stream>>>(done, h0, c0, whh_bf, gates, hseq, out);
  k3_heads<<<dim3(2048), dim3(256), 0, stream>>>(hseq, wp1s, wv1s, b_p1, W_p2, b_p2,
                                                 b_v1, W_v2, b_v2, out);
}